// Round 1
// baseline (2445.320 us; speedup 1.0000x reference)
//
#include <hip/hip_runtime.h>
#include <stdint.h>
#include <stddef.h>

typedef unsigned short u16;
typedef __attribute__((ext_vector_type(8))) short short8;
typedef __attribute__((ext_vector_type(4))) float f32x4;

#define DEV static __device__ __forceinline__

DEV float bf2f(u16 u){ return __uint_as_float(((unsigned)u)<<16); }
DEV u16 f2bf(float f){ unsigned x=__float_as_uint(f); return (u16)((x + 0x7fffu + ((x>>16)&1u))>>16); }

DEV float wsum(float v){
#pragma unroll
  for(int o=32;o;o>>=1) v += __shfl_xor(v,o);
  return v;
}
DEV float wmax(float v){
#pragma unroll
  for(int o=32;o;o>>=1) v = fmaxf(v,__shfl_xor(v,o));
  return v;
}
DEV float sigm(float x){ return __fdividef(1.f, 1.f+__expf(-x)); }
DEV float tanhx(float x){ float e=__expf(-2.f*fabsf(x)); float t=__fdividef(1.f-e,1.f+e); return x<0.f?-t:t; }

DEV f32x4 mfma16(short8 a, short8 b, f32x4 c){
  asm("v_mfma_f32_16x16x32_bf16 %0, %1, %2, %0" : "+v"(c) : "v"(a), "v"(b));
  return c;
}
DEV void gll16(const void* g, void* l){
  __builtin_amdgcn_global_load_lds((const __attribute__((address_space(1))) void*)g,
                                   (__attribute__((address_space(3))) void*)l, 16, 0, 0);
}

DEV void pack8(u16* dst, const float* src){
  const float4 a=*(const float4*)(src);
  const float4 b=*(const float4*)(src+4);
  short8 o;
  o[0]=(short)f2bf(a.x); o[1]=(short)f2bf(a.y); o[2]=(short)f2bf(a.z); o[3]=(short)f2bf(a.w);
  o[4]=(short)f2bf(b.x); o[5]=(short)f2bf(b.y); o[6]=(short)f2bf(b.z); o[7]=(short)f2bf(b.w);
  *(short8*)dst=o;
}
DEV void zero8(u16* dst){
  short8 z;
#pragma unroll
  for(int e=0;e<8;++e) z[e]=0;
  *(short8*)dst=z;
}

// ---------------------------------------------------------------------------
// setup: fp32->bf16 casts, weight reorders, embedding gather, combined bias.
// Gate rows reordered unit-major: new row r <-> orig row o=((r&3)<<9)+(r>>2),
// so a 128-col GEMM tile holds complete (i,f,g,o) quadruples for 32 units.
// ---------------------------------------------------------------------------
__global__ __launch_bounds__(256) void setup_cast(
  const float* __restrict__ feats, const int* __restrict__ captions,
  const float* __restrict__ embW, const float* __restrict__ Wf_w,
  const float* __restrict__ Wh_w, const float* __restrict__ W_ih,
  const float* __restrict__ W_hh, const float* __restrict__ b_ih,
  const float* __restrict__ b_hh, const float* __restrict__ out_w,
  u16* __restrict__ feats_bf, u16* __restrict__ outw_bf, u16* __restrict__ Wc,
  u16* __restrict__ WihE, u16* __restrict__ embx, u16* __restrict__ Whw_bf,
  u16* __restrict__ Wf_bf, float* __restrict__ bias_comb)
{
  const long long o0=12845056LL,o1=28246016LL,o2=30343168LL,o3=31391744LL,
                  o4=32702464LL,o5=32964608LL,o6=33226752LL,total=33228800LL;
  for (long long i8=((long long)blockIdx.x*256+threadIdx.x)*8; i8<total;
       i8+=(long long)gridDim.x*256*8){
    const long long i=i8;
    if (i<o0){ pack8(feats_bf+i, feats+i); }
    else if (i<o1){ const long long j=i-o0; const int r=(int)(j>>9);
      if (r<30000) pack8(outw_bf+j, out_w+j); else zero8(outw_bf+j); }
    else if (i<o2){ const long long j=i-o1; const int r=(int)(j>>10), k=(int)(j&1023);
      const int o=((r&3)<<9)+(r>>2);
      const float* s=(k<512)? (W_ih+(size_t)o*1024+512+k) : (W_hh+(size_t)o*512+(k-512));
      pack8(Wc+j, s); }
    else if (i<o3){ const long long j=i-o2; const int r=(int)(j>>9), k=(int)(j&511);
      const int o=((r&3)<<9)+(r>>2);
      pack8(WihE+j, W_ih+(size_t)o*1024+k); }
    else if (i<o4){ const long long j=i-o3; const int m=(int)(j>>9), e=(int)(j&511);
      const int b=m/20, tt=m-b*20; const int idx=captions[b*21+tt];
      if (idx) pack8(embx+j, embW+(size_t)idx*512+e); else zero8(embx+j); }
    else if (i<o5){ const long long j=i-o4; pack8(Whw_bf+j, Wh_w+j); }
    else if (i<o6){ const long long j=i-o5; pack8(Wf_bf+j, Wf_w+j); }
    else { const long long j=i-o6;
      for(int e=0;e<8;++e){ const int r=(int)(j+e); const int o=((r&3)<<9)+(r>>2);
        bias_comb[r]=b_ih[o]+b_hh[o]; } }
  }
}

// ---------------------------------------------------------------------------
// prep: gfeat = mean(feats), h0/c0 (fp32 vector). Writes h0 (bf16) into xs0
// h-slot, c0 (fp32) into cbuf.
// ---------------------------------------------------------------------------
__global__ __launch_bounds__(256) void prep(
  const float* __restrict__ feats, const float* __restrict__ init_w,
  const float* __restrict__ init_b, const float* __restrict__ initc_w,
  const float* __restrict__ initc_b, u16* __restrict__ xs0, float* __restrict__ cbuf)
{
  const int b=blockIdx.x, tid=threadIdx.x, lane=tid&63, w=tid>>6;
  __shared__ float gf[512];
  const float* fb=feats+(size_t)b*196*512;
  float a0=0.f,a1=0.f;
  for(int n=0;n<196;++n){ a0+=fb[(size_t)n*512+tid]; a1+=fb[(size_t)n*512+tid+256]; }
  gf[tid]=a0*(1.f/196.f); gf[tid+256]=a1*(1.f/196.f);
  __syncthreads();
  const int kb=lane*8;
  float g8[8];
#pragma unroll
  for(int e=0;e<8;++e) g8[e]=gf[kb+e];
  for(int j=w*128;j<w*128+128;++j){
    const float* r1=init_w+(size_t)j*512+kb;
    const float* r2=initc_w+(size_t)j*512+kb;
    float s1=0.f,s2=0.f;
#pragma unroll
    for(int e=0;e<8;++e){ s1+=g8[e]*r1[e]; s2+=g8[e]*r2[e]; }
    s1=wsum(s1); s2=wsum(s2);
    if(lane==(j&63)){ xs0[b*1024+512+j]=f2bf(s1+init_b[j]); cbuf[b*512+j]=s2+initc_b[j]; }
  }
}

// ---------------------------------------------------------------------------
// attn_step: per-b block (128 blocks x 512 threads).
// hproj -> scores (tanh) -> softmax(196) -> ctx. ctx written as bf16 into the
// ctx half of xs (the gates-GEMM A operand).
// ---------------------------------------------------------------------------
__global__ __launch_bounds__(512) void attn_step(
  const u16* __restrict__ fproj, const u16* __restrict__ feats_bf,
  u16* __restrict__ xs, const u16* __restrict__ Whw,
  const float* __restrict__ Whb, const float* __restrict__ vw,
  const float* __restrict__ vb)
{
  const int b=blockIdx.x, tid=threadIdx.x, lane=tid&63, w=tid>>6;
  __shared__ float hs[512], hp[512], sc[256], red[8];
  __shared__ float cpart[8][512];
  hs[tid]=bf2f(xs[b*1024+512+tid]);
  __syncthreads();
  const int kb=lane*8;
  float h8[8];
#pragma unroll
  for(int e=0;e<8;++e) h8[e]=hs[kb+e];
  // hproj: wave w owns j in [w*64, w*64+64)
  for(int j=w*64;j<w*64+64;++j){
    short8 wv=*(const short8*)(Whw+(size_t)j*512+kb);
    float s=0.f;
#pragma unroll
    for(int e=0;e<8;++e) s+=h8[e]*bf2f((u16)wv[e]);
    s=wsum(s);
    if(lane==(j&63)) hp[j]=s+Whb[j];
  }
  __syncthreads();
  float p8[8], v8[8];
#pragma unroll
  for(int e=0;e<8;++e){ p8[e]=hp[kb+e]; v8[e]=vw[kb+e]; }
  for(int n=w;n<196;n+=8){
    short8 fv=*(const short8*)(fproj+((size_t)b*196+n)*512+kb);
    float s=0.f;
#pragma unroll
    for(int e=0;e<8;++e) s+=v8[e]*tanhx(bf2f((u16)fv[e])+p8[e]);
    s=wsum(s);
    if(lane==0) sc[n]=s+vb[0];
  }
  __syncthreads();
  // softmax over 196
  float xv=(tid<196)? sc[tid] : -3.0e38f;
  float mx=wmax(xv);
  if(lane==0) red[w]=mx;
  __syncthreads();
  float mm=red[0];
#pragma unroll
  for(int i=1;i<8;++i) mm=fmaxf(mm,red[i]);
  float pv=(tid<196)? __expf(xv-mm) : 0.f;
  float ps=wsum(pv);
  __syncthreads();
  if(lane==0) red[w]=ps;
  __syncthreads();
  float tot=red[0];
#pragma unroll
  for(int i=1;i<8;++i) tot+=red[i];
  if(tid<196) sc[tid]=__fdividef(pv,tot);
  __syncthreads();
  // ctx: wave w accumulates n = w, w+8, ... ; 16B/lane loads
  float a8[8];
#pragma unroll
  for(int e=0;e<8;++e) a8[e]=0.f;
  for(int n=w;n<196;n+=8){
    short8 fv=*(const short8*)(feats_bf+((size_t)b*196+n)*512+kb);
    const float wn=sc[n];
#pragma unroll
    for(int e=0;e<8;++e) a8[e]+=wn*bf2f((u16)fv[e]);
  }
#pragma unroll
  for(int e=0;e<8;++e) cpart[w][kb+e]=a8[e];
  __syncthreads();
  float acc=0.f;
#pragma unroll
  for(int i=0;i<8;++i) acc+=cpart[i][tid];
  xs[b*1024+tid]=f2bf(acc);
}

// ---------------------------------------------------------------------------
// gemm_bt: C[M,N] = A[M,K] * B[N,K]^T  (bf16 in, fp32 acc), 128x128 tile,
// 4 waves x (4x4) 16x16x32 MFMA frags, BK=32, global_load_lds staging.
// MODE 0: bf16 out + bias (fproj)        MODE 1: f32 out + bias (gemb)
// MODE 2: f32 out + bias, col guard (logits -> d_out)
// MODE 3: gates: += gemb, LSTM epilogue via LDS transpose
// ---------------------------------------------------------------------------
template<int MODE>
__global__ __launch_bounds__(256) void gemm_bt(
  const u16* __restrict__ A, int lda, const u16* __restrict__ Bw, int ldb, int K,
  const float* __restrict__ bias, float* __restrict__ outf, u16* __restrict__ outb,
  int ncols, const float* __restrict__ gemb, float* __restrict__ cbuf,
  u16* __restrict__ xs_next, u16* __restrict__ h_all, int t)
{
  const int bm=blockIdx.y*128, bn=blockIdx.x*128;
  const int tid=threadIdx.x, lane=tid&63, wave=tid>>6;
  const int wr=(wave>>1)*64, wc=(wave&1)*64;
  __shared__ u16 As[128*32], Bs[128*32];
  f32x4 acc[4][4]={};
  const int srow=tid>>2, scol=(tid&3)*8;
  for(int k0=0;k0<K;k0+=32){
    gll16(A +(size_t)(bm+srow)*lda    +k0+scol, As+tid*8);
    gll16(A +(size_t)(bm+64+srow)*lda +k0+scol, As+2048+tid*8);
    gll16(Bw+(size_t)(bn+srow)*ldb    +k0+scol, Bs+tid*8);
    gll16(Bw+(size_t)(bn+64+srow)*ldb +k0+scol, Bs+2048+tid*8);
    __syncthreads();
    short8 af[4], bfr[4];
    const int ro=lane&15, ko=(lane>>4)*8;
#pragma unroll
    for(int m=0;m<4;++m) af[m]=*(const short8*)(As+(wr+m*16+ro)*32+ko);
#pragma unroll
    for(int n=0;n<4;++n) bfr[n]=*(const short8*)(Bs+(wc+n*16+ro)*32+ko);
#pragma unroll
    for(int m=0;m<4;++m)
#pragma unroll
      for(int n=0;n<4;++n) acc[m][n]=mfma16(af[m],bfr[n],acc[m][n]);
    __syncthreads();
  }
  asm volatile("s_nop 7\ns_nop 7\ns_nop 7");  // MFMA->VALU hazard guard
  const int ro4=(lane>>4)*4, co=lane&15;
  if constexpr (MODE==0){
#pragma unroll
    for(int m=0;m<4;++m)
#pragma unroll
      for(int n=0;n<4;++n)
#pragma unroll
        for(int j=0;j<4;++j){
          const int r=bm+wr+m*16+ro4+j, c=bn+wc+n*16+co;
          outb[(size_t)r*ncols+c]=f2bf(acc[m][n][j]+bias[c]);
        }
  } else if constexpr (MODE==1){
#pragma unroll
    for(int m=0;m<4;++m)
#pragma unroll
      for(int n=0;n<4;++n)
#pragma unroll
        for(int j=0;j<4;++j){
          const int r=bm+wr+m*16+ro4+j, c=bn+wc+n*16+co;
          outf[(size_t)r*ncols+c]=acc[m][n][j]+bias[c];
        }
  } else if constexpr (MODE==2){
#pragma unroll
    for(int m=0;m<4;++m)
#pragma unroll
      for(int n=0;n<4;++n)
#pragma unroll
        for(int j=0;j<4;++j){
          const int r=bm+wr+m*16+ro4+j, c=bn+wc+n*16+co;
          if (c<ncols) outf[(size_t)r*ncols+c]=acc[m][n][j]+bias[c];
        }
  } else {
    // gates + LSTM epilogue. bm==0, rows are batch. Two 64-col passes through
    // a [128][66] LDS tile so each thread sees complete i,f,g,o quadruples.
    __shared__ float gt[128][66];
    for(int p=0;p<2;++p){
      if ((wave&1)==p){
#pragma unroll
        for(int m=0;m<4;++m)
#pragma unroll
          for(int n=0;n<4;++n)
#pragma unroll
            for(int j=0;j<4;++j){
              const int r=wr+m*16+ro4+j;
              const int lc=n*16+co;
              gt[r][lc]=acc[m][n][j]+gemb[((size_t)r*20+t)*2048+(bn+p*64+lc)];
            }
      }
      __syncthreads();
      const int ub=(bn+p*64)>>2;
      for(int i=0;i<8;++i){
        const int idx=i*256+tid, bb=idx&127, ul=idx>>7;
        const float gi=gt[bb][ul*4+0], gf=gt[bb][ul*4+1];
        const float gg=gt[bb][ul*4+2], go=gt[bb][ul*4+3];
        const int u=ub+ul;
        const float cn=sigm(gf)*cbuf[bb*512+u]+sigm(gi)*tanhx(gg);
        const float hn=sigm(go)*tanhx(cn);
        cbuf[bb*512+u]=cn;
        const u16 hb=f2bf(hn);
        xs_next[bb*1024+512+u]=hb;
        h_all[((size_t)bb*20+t)*512+u]=hb;
      }
      __syncthreads();
    }
  }
}

// ---------------------------------------------------------------------------
extern "C" void kernel_launch(void* const* d_in, const int* in_sizes, int n_in,
                              void* d_out, int out_size, void* d_ws, size_t ws_size,
                              hipStream_t stream) {
  const float* feats   =(const float*)d_in[0];
  const int*   captions=(const int*)  d_in[1];
  const float* embW    =(const float*)d_in[2];
  const float* Wf_w    =(const float*)d_in[3];
  const float* Wf_b    =(const float*)d_in[4];
  const float* Wh_w    =(const float*)d_in[5];
  const float* Wh_b    =(const float*)d_in[6];
  const float* v_w     =(const float*)d_in[7];
  const float* v_b     =(const float*)d_in[8];
  const float* W_ih    =(const float*)d_in[9];
  const float* W_hh    =(const float*)d_in[10];
  const float* b_ih    =(const float*)d_in[11];
  const float* b_hh    =(const float*)d_in[12];
  const float* init_w  =(const float*)d_in[13];
  const float* init_b  =(const float*)d_in[14];
  const float* initc_w =(const float*)d_in[15];
  const float* initc_b =(const float*)d_in[16];
  const float* out_w   =(const float*)d_in[17];
  const float* out_b   =(const float*)d_in[18];
  float* out=(float*)d_out;
  char* ws=(char*)d_ws;

  u16*   feats_bf =(u16*)  (ws+0);
  u16*   fproj    =(u16*)  (ws+25690112);
  u16*   outw_bf  =(u16*)  (ws+51380224);
  u16*   Wc       =(u16*)  (ws+82182144);
  u16*   WihE     =(u16*)  (ws+86376448);
  u16*   Whw_bf   =(u16*)  (ws+88473600);
  u16*   Wf_bf    =(u16*)  (ws+88997888);
  u16*   embx     =(u16*)  (ws+89522176);
  u16*   h_all    =(u16*)  (ws+92143616);
  u16*   xs0      =(u16*)  (ws+94765056);
  u16*   xs1      =(u16*)  (ws+95027200);
  float* gemb     =(float*)(ws+95289344);
  float* cbuf     =(float*)(ws+116260864);
  float* bias_comb=(float*)(ws+116523008);

  setup_cast<<<4096,256,0,stream>>>(feats,captions,embW,Wf_w,Wh_w,W_ih,W_hh,b_ih,b_hh,out_w,
                                    feats_bf,outw_bf,Wc,WihE,embx,Whw_bf,Wf_bf,bias_comb);
  prep<<<128,256,0,stream>>>(feats,init_w,init_b,initc_w,initc_b,xs0,cbuf);
  // fproj = feats_bf @ Wf^T + Wf_b  (25088 x 512, K=512) -> bf16
  gemm_bt<0><<<dim3(4,196),256,0,stream>>>(feats_bf,512,Wf_bf,512,512,
      Wf_b,nullptr,fproj,512,nullptr,nullptr,nullptr,nullptr,0);
  // gemb = embx @ WihE^T + (b_ih+b_hh)  (2560 x 2048, K=512) -> f32
  gemm_bt<1><<<dim3(16,20),256,0,stream>>>(embx,512,WihE,512,512,
      bias_comb,gemb,nullptr,2048,nullptr,nullptr,nullptr,nullptr,0);

  for(int t=0;t<20;++t){
    u16* xc=(t&1)? xs1 : xs0;
    u16* xn=(t&1)? xs0 : xs1;
    attn_step<<<128,512,0,stream>>>(fproj,feats_bf,xc,Whw_bf,Wh_b,v_w,v_b);
    gemm_bt<3><<<dim3(16,1),256,0,stream>>>(xc,1024,Wc,1024,1024,
        nullptr,nullptr,nullptr,2048,gemb,cbuf,xn,h_all,t);
  }
  // logits = h_all @ out_w^T + out_b  (2560 x 30000, K=512) -> d_out (f32)
  gemm_bt<2><<<dim3(235,20),256,0,stream>>>(h_all,512,outw_bf,512,512,
      out_b,out,nullptr,30000,nullptr,nullptr,nullptr,nullptr,0);
}

// Round 6
// 1797.788 us; speedup vs baseline: 1.3602x; 1.3602x over previous
//
#include <hip/hip_runtime.h>
#include <stdint.h>
#include <stddef.h>

typedef unsigned short u16;
typedef __attribute__((ext_vector_type(8))) short short8;
typedef __attribute__((ext_vector_type(4))) float f32x4;

#define DEV static __device__ __forceinline__

DEV float bf2f(u16 u){ return __uint_as_float(((unsigned)u)<<16); }
DEV u16 f2bf(float f){ unsigned x=__float_as_uint(f); return (u16)((x + 0x7fffu + ((x>>16)&1u))>>16); }

DEV float wsum(float v){
#pragma unroll
  for(int o=32;o;o>>=1) v += __shfl_xor(v,o);
  return v;
}
DEV float wmax(float v){
#pragma unroll
  for(int o=32;o;o>>=1) v = fmaxf(v,__shfl_xor(v,o));
  return v;
}
DEV float sigm(float x){ return __fdividef(1.f, 1.f+__expf(-x)); }
DEV float tanhx(float x){ float e=__expf(-2.f*fabsf(x)); float t=__fdividef(1.f-e,1.f+e); return x<0.f?-t:t; }

DEV f32x4 mfma16(short8 a, short8 b, f32x4 c){
  asm("v_mfma_f32_16x16x32_bf16 %0, %1, %2, %0" : "+v"(c) : "v"(a), "v"(b));
  return c;
}
DEV void gll16(const void* g, void* l){
  __builtin_amdgcn_global_load_lds((const __attribute__((address_space(1))) void*)g,
                                   (__attribute__((address_space(3))) void*)l, 16, 0, 0);
}

DEV void pack8(u16* dst, const float* src){
  const float4 a=*(const float4*)(src);
  const float4 b=*(const float4*)(src+4);
  short8 o;
  o[0]=(short)f2bf(a.x); o[1]=(short)f2bf(a.y); o[2]=(short)f2bf(a.z); o[3]=(short)f2bf(a.w);
  o[4]=(short)f2bf(b.x); o[5]=(short)f2bf(b.y); o[6]=(short)f2bf(b.z); o[7]=(short)f2bf(b.w);
  *(short8*)dst=o;
}
DEV void zero8(u16* dst){
  short8 z;
#pragma unroll
  for(int e=0;e<8;++e) z[e]=0;
  *(short8*)dst=z;
}

// ---------------------------------------------------------------------------
// setup: fp32->bf16 casts, weight reorders, embedding gather, combined bias.
// Gate rows unit-major: new row r <-> orig row o=((r&3)<<9)+(r>>2).
// ---------------------------------------------------------------------------
__global__ __launch_bounds__(256) void setup_cast(
  const float* __restrict__ feats, const int* __restrict__ captions,
  const float* __restrict__ embW, const float* __restrict__ Wf_w,
  const float* __restrict__ Wh_w, const float* __restrict__ W_ih,
  const float* __restrict__ W_hh, const float* __restrict__ b_ih,
  const float* __restrict__ b_hh, const float* __restrict__ out_w,
  u16* __restrict__ feats_bf, u16* __restrict__ outw_bf, u16* __restrict__ Wc,
  u16* __restrict__ WihE, u16* __restrict__ embx, u16* __restrict__ Whw_bf,
  u16* __restrict__ Wf_bf, float* __restrict__ bias_comb)
{
  const long long o0=12845056LL,o1=28246016LL,o2=30343168LL,o3=31391744LL,
                  o4=32702464LL,o5=32964608LL,o6=33226752LL,total=33228800LL;
  for (long long i8=((long long)blockIdx.x*256+threadIdx.x)*8; i8<total;
       i8+=(long long)gridDim.x*256*8){
    const long long i=i8;
    if (i<o0){ pack8(feats_bf+i, feats+i); }
    else if (i<o1){ const long long j=i-o0; const int r=(int)(j>>9);
      if (r<30000) pack8(outw_bf+j, out_w+j); else zero8(outw_bf+j); }
    else if (i<o2){ const long long j=i-o1; const int r=(int)(j>>10), k=(int)(j&1023);
      const int o=((r&3)<<9)+(r>>2);
      const float* s=(k<512)? (W_ih+(size_t)o*1024+512+k) : (W_hh+(size_t)o*512+(k-512));
      pack8(Wc+j, s); }
    else if (i<o3){ const long long j=i-o2; const int r=(int)(j>>9), k=(int)(j&511);
      const int o=((r&3)<<9)+(r>>2);
      pack8(WihE+j, W_ih+(size_t)o*1024+k); }
    else if (i<o4){ const long long j=i-o3; const int m=(int)(j>>9), e=(int)(j&511);
      const int b=m/20, tt=m-b*20; const int idx=captions[b*21+tt];
      if (idx) pack8(embx+j, embW+(size_t)idx*512+e); else zero8(embx+j); }
    else if (i<o5){ const long long j=i-o4; pack8(Whw_bf+j, Wh_w+j); }
    else if (i<o6){ const long long j=i-o5; pack8(Wf_bf+j, Wf_w+j); }
    else { const long long j=i-o6;
      for(int e=0;e<8;++e){ const int r=(int)(j+e); const int o=((r&3)<<9)+(r>>2);
        bias_comb[r]=b_ih[o]+b_hh[o]; } }
  }
}

// ---------------------------------------------------------------------------
// prep: gfeat = mean(feats), h0/c0. h0 (bf16) -> xs0 h-slot, c0 (fp32) -> cbuf.
// ---------------------------------------------------------------------------
__global__ __launch_bounds__(256) void prep(
  const float* __restrict__ feats, const float* __restrict__ init_w,
  const float* __restrict__ init_b, const float* __restrict__ initc_w,
  const float* __restrict__ initc_b, u16* __restrict__ xs0, float* __restrict__ cbuf)
{
  const int b=blockIdx.x, tid=threadIdx.x, lane=tid&63, w=tid>>6;
  __shared__ float gf[512];
  const float* fb=feats+(size_t)b*196*512;
  float a0=0.f,a1=0.f;
  for(int n=0;n<196;++n){ a0+=fb[(size_t)n*512+tid]; a1+=fb[(size_t)n*512+tid+256]; }
  gf[tid]=a0*(1.f/196.f); gf[tid+256]=a1*(1.f/196.f);
  __syncthreads();
  const int kb=lane*8;
  float g8[8];
#pragma unroll
  for(int e=0;e<8;++e) g8[e]=gf[kb+e];
  for(int j=w*128;j<w*128+128;++j){
    const float* r1=init_w+(size_t)j*512+kb;
    const float* r2=initc_w+(size_t)j*512+kb;
    float s1=0.f,s2=0.f;
#pragma unroll
    for(int e=0;e<8;++e){ s1+=g8[e]*r1[e]; s2+=g8[e]*r2[e]; }
    s1=wsum(s1); s2=wsum(s2);
    if(lane==(j&63)){ xs0[b*1024+512+j]=f2bf(s1+init_b[j]); cbuf[b*512+j]=s2+initc_b[j]; }
  }
}

// ---------------------------------------------------------------------------
// attn_step: 128 blocks x 1024 threads (16 waves), round-1-identical math.
// hproj: wave w owns rows [32w,32w+32), 2-row ILP, same dot+wsum as round 1.
// scores: n = w + 16*i. softmax(196): 16-wave reduce. ctx: stride-16 partials.
// ---------------------------------------------------------------------------
__global__ __launch_bounds__(1024) void attn_step(
  const u16* __restrict__ fproj, const u16* __restrict__ feats_bf,
  u16* __restrict__ xs, const u16* __restrict__ Whw,
  const float* __restrict__ Whb, const float* __restrict__ vw,
  const float* __restrict__ vb)
{
  const int b=blockIdx.x, tid=threadIdx.x, lane=tid&63, w=tid>>6;
  __shared__ float part[16][512];
  __shared__ float hsf[512], hp[512], sc[208], red[16];
  if (tid<512) hsf[tid]=bf2f(xs[b*1024+512+tid]);
  __syncthreads();
  const int kb=lane*8;
  float h8[8];
#pragma unroll
  for(int e=0;e<8;++e) h8[e]=hsf[kb+e];
  // hproj: wave w owns rows [32w, 32w+32), 2 rows per iteration
  for(int jj=0;jj<32;jj+=2){
    const int j=w*32+jj;
    short8 w0=*(const short8*)(Whw+(size_t)j*512+kb);
    short8 w1=*(const short8*)(Whw+(size_t)(j+1)*512+kb);
    float s0=0.f,s1=0.f;
#pragma unroll
    for(int e=0;e<8;++e){
      s0+=h8[e]*bf2f((u16)w0[e]);
      s1+=h8[e]*bf2f((u16)w1[e]);
    }
    s0=wsum(s0); s1=wsum(s1);
    if(lane==0){ hp[j]=s0+Whb[j]; hp[j+1]=s1+Whb[j+1]; }
  }
  __syncthreads();
  // scores: wave w handles n = w + 16*i
  float p8[8], v8[8];
#pragma unroll
  for(int e=0;e<8;++e){ p8[e]=hp[kb+e]; v8[e]=vw[kb+e]; }
  const float vb0=vb[0];
  for(int n=w;n<196;n+=16){
    short8 f0=*(const short8*)(fproj+((size_t)b*196+n)*512+kb);
    float s0=0.f;
#pragma unroll
    for(int e=0;e<8;++e) s0+=v8[e]*tanhx(bf2f((u16)f0[e])+p8[e]);
    s0=wsum(s0);
    if(lane==0) sc[n]=s0+vb0;
  }
  __syncthreads();
  // softmax over 196
  float xv=(tid<196)? sc[tid] : -3.0e38f;
  float mx=wmax(xv);
  if(lane==0) red[w]=mx;
  __syncthreads();
  float mm=red[0];
#pragma unroll
  for(int i=1;i<16;++i) mm=fmaxf(mm,red[i]);
  float pv=(tid<196)? __expf(xv-mm) : 0.f;
  float ps=wsum(pv);
  __syncthreads();
  if(lane==0) red[w]=ps;
  __syncthreads();
  float tot=red[0];
#pragma unroll
  for(int i=1;i<16;++i) tot+=red[i];
  if(tid<196) sc[tid]=__fdividef(pv,tot);
  __syncthreads();
  // ctx partials: wave w accumulates n = w + 16*i
  float a8[8];
#pragma unroll
  for(int e=0;e<8;++e) a8[e]=0.f;
  for(int n=w;n<196;n+=16){
    short8 fv=*(const short8*)(feats_bf+((size_t)b*196+n)*512+kb);
    const float wn=sc[n];
#pragma unroll
    for(int e=0;e<8;++e) a8[e]+=wn*bf2f((u16)fv[e]);
  }
  *(float4*)&part[w][kb]  =*(float4*)&a8[0];
  *(float4*)&part[w][kb+4]=*(float4*)&a8[4];
  __syncthreads();
  if (tid<512){
    float s=0.f;
#pragma unroll
    for(int i=0;i<16;++i) s+=part[i][tid];
    xs[b*1024+tid]=f2bf(s);
  }
}

// ---------------------------------------------------------------------------
// gemm_bt: C[M,N] = A[M,K] * B[N,K]^T, 128x128 tile, m97 structure.
// MODE 0: bf16 out + bias   MODE 1: f32 out + bias   MODE 2: f32 + col guard
// MODE 3: gates + LSTM epilogue (round-1 PROVEN version, restored verbatim)
// ---------------------------------------------------------------------------
template<int MODE>
__global__ __launch_bounds__(256) void gemm_bt(
  const u16* __restrict__ A, int lda, const u16* __restrict__ Bw, int ldb, int K,
  const float* __restrict__ bias, float* __restrict__ outf, u16* __restrict__ outb,
  int ncols, const float* __restrict__ gemb, float* __restrict__ cbuf,
  u16* __restrict__ xs_next, u16* __restrict__ h_all, int t)
{
  const int bm=blockIdx.y*128, bn=blockIdx.x*128;
  const int tid=threadIdx.x, lane=tid&63, wave=tid>>6;
  const int wr=(wave>>1)*64, wc=(wave&1)*64;
  __shared__ u16 As[128*32], Bs[128*32];
  f32x4 acc[4][4]={};
  const int srow=tid>>2, scol=(tid&3)*8;
  for(int k0=0;k0<K;k0+=32){
    gll16(A +(size_t)(bm+srow)*lda    +k0+scol, As+tid*8);
    gll16(A +(size_t)(bm+64+srow)*lda +k0+scol, As+2048+tid*8);
    gll16(Bw+(size_t)(bn+srow)*ldb    +k0+scol, Bs+tid*8);
    gll16(Bw+(size_t)(bn+64+srow)*ldb +k0+scol, Bs+2048+tid*8);
    __syncthreads();
    short8 af[4], bfr[4];
    const int ro=lane&15, ko=(lane>>4)*8;
#pragma unroll
    for(int m=0;m<4;++m) af[m]=*(const short8*)(As+(wr+m*16+ro)*32+ko);
#pragma unroll
    for(int n=0;n<4;++n) bfr[n]=*(const short8*)(Bs+(wc+n*16+ro)*32+ko);
#pragma unroll
    for(int m=0;m<4;++m)
#pragma unroll
      for(int n=0;n<4;++n) acc[m][n]=mfma16(af[m],bfr[n],acc[m][n]);
    __syncthreads();
  }
  asm volatile("s_nop 7\ns_nop 7\ns_nop 7");  // MFMA->VALU hazard guard
  const int ro4=(lane>>4)*4, co=lane&15;
  if constexpr (MODE==0){
#pragma unroll
    for(int m=0;m<4;++m)
#pragma unroll
      for(int n=0;n<4;++n)
#pragma unroll
        for(int j=0;j<4;++j){
          const int r=bm+wr+m*16+ro4+j, c=bn+wc+n*16+co;
          outb[(size_t)r*ncols+c]=f2bf(acc[m][n][j]+bias[c]);
        }
  } else if constexpr (MODE==1){
#pragma unroll
    for(int m=0;m<4;++m)
#pragma unroll
      for(int n=0;n<4;++n)
#pragma unroll
        for(int j=0;j<4;++j){
          const int r=bm+wr+m*16+ro4+j, c=bn+wc+n*16+co;
          outf[(size_t)r*ncols+c]=acc[m][n][j]+bias[c];
        }
  } else if constexpr (MODE==2){
#pragma unroll
    for(int m=0;m<4;++m)
#pragma unroll
      for(int n=0;n<4;++n)
#pragma unroll
        for(int j=0;j<4;++j){
          const int r=bm+wr+m*16+ro4+j, c=bn+wc+n*16+co;
          if (c<ncols) outf[(size_t)r*ncols+c]=acc[m][n][j]+bias[c];
        }
  } else {
    // gates + LSTM epilogue. bm==0, rows are batch. Two 64-col passes through
    // a [128][66] LDS tile so each thread sees complete i,f,g,o quadruples.
    __shared__ float gt[128][66];
    for(int p=0;p<2;++p){
      if ((wave&1)==p){
#pragma unroll
        for(int m=0;m<4;++m)
#pragma unroll
          for(int n=0;n<4;++n)
#pragma unroll
            for(int j=0;j<4;++j){
              const int r=wr+m*16+ro4+j;
              const int lc=n*16+co;
              gt[r][lc]=acc[m][n][j]+gemb[((size_t)r*20+t)*2048+(bn+p*64+lc)];
            }
      }
      __syncthreads();
      const int ub=(bn+p*64)>>2;
      for(int i=0;i<8;++i){
        const int idx=i*256+tid, bb=idx&127, ul=idx>>7;
        const float gi=gt[bb][ul*4+0], gf=gt[bb][ul*4+1];
        const float gg=gt[bb][ul*4+2], go=gt[bb][ul*4+3];
        const int u=ub+ul;
        const float cn=sigm(gf)*cbuf[bb*512+u]+sigm(gi)*tanhx(gg);
        const float hn=sigm(go)*tanhx(cn);
        cbuf[bb*512+u]=cn;
        const u16 hb=f2bf(hn);
        xs_next[bb*1024+512+u]=hb;
        h_all[((size_t)bb*20+t)*512+u]=hb;
      }
      __syncthreads();
    }
  }
}

// ---------------------------------------------------------------------------
extern "C" void kernel_launch(void* const* d_in, const int* in_sizes, int n_in,
                              void* d_out, int out_size, void* d_ws, size_t ws_size,
                              hipStream_t stream) {
  const float* feats   =(const float*)d_in[0];
  const int*   captions=(const int*)  d_in[1];
  const float* embW    =(const float*)d_in[2];
  const float* Wf_w    =(const float*)d_in[3];
  const float* Wf_b    =(const float*)d_in[4];
  const float* Wh_w    =(const float*)d_in[5];
  const float* Wh_b    =(const float*)d_in[6];
  const float* v_w     =(const float*)d_in[7];
  const float* v_b     =(const float*)d_in[8];
  const float* W_ih    =(const float*)d_in[9];
  const float* W_hh    =(const float*)d_in[10];
  const float* b_ih    =(const float*)d_in[11];
  const float* b_hh    =(const float*)d_in[12];
  const float* init_w  =(const float*)d_in[13];
  const float* init_b  =(const float*)d_in[14];
  const float* initc_w =(const float*)d_in[15];
  const float* initc_b =(const float*)d_in[16];
  const float* out_w   =(const float*)d_in[17];
  const float* out_b   =(const float*)d_in[18];
  float* out=(float*)d_out;
  char* ws=(char*)d_ws;

  u16*   feats_bf =(u16*)  (ws+0);
  u16*   fproj    =(u16*)  (ws+25690112);
  u16*   outw_bf  =(u16*)  (ws+51380224);
  u16*   Wc       =(u16*)  (ws+82182144);
  u16*   WihE     =(u16*)  (ws+86376448);
  u16*   Whw_bf   =(u16*)  (ws+88473600);
  u16*   Wf_bf    =(u16*)  (ws+88997888);
  u16*   embx     =(u16*)  (ws+89522176);
  u16*   h_all    =(u16*)  (ws+92143616);
  u16*   xs0      =(u16*)  (ws+94765056);
  u16*   xs1      =(u16*)  (ws+95027200);
  float* gemb     =(float*)(ws+95289344);
  float* cbuf     =(float*)(ws+116260864);
  float* bias_comb=(float*)(ws+116523008);

  setup_cast<<<4096,256,0,stream>>>(feats,captions,embW,Wf_w,Wh_w,W_ih,W_hh,b_ih,b_hh,out_w,
                                    feats_bf,outw_bf,Wc,WihE,embx,Whw_bf,Wf_bf,bias_comb);
  prep<<<128,256,0,stream>>>(feats,init_w,init_b,initc_w,initc_b,xs0,cbuf);
  // fproj = feats_bf @ Wf^T + Wf_b  (25088 x 512, K=512) -> bf16
  gemm_bt<0><<<dim3(4,196),256,0,stream>>>(feats_bf,512,Wf_bf,512,512,
      Wf_b,nullptr,fproj,512,nullptr,nullptr,nullptr,nullptr,0);
  // gemb = embx @ WihE^T + (b_ih+b_hh)  (2560 x 2048, K=512) -> f32
  gemm_bt<1><<<dim3(16,20),256,0,stream>>>(embx,512,WihE,512,512,
      bias_comb,gemb,nullptr,2048,nullptr,nullptr,nullptr,nullptr,0);

  for(int t=0;t<20;++t){
    u16* xc=(t&1)? xs1 : xs0;
    u16* xn=(t&1)? xs0 : xs1;
    attn_step<<<128,1024,0,stream>>>(fproj,feats_bf,xc,Whw_bf,Wh_b,v_w,v_b);
    gemm_bt<3><<<dim3(16,1),256,0,stream>>>(xc,1024,Wc,1024,1024,
        nullptr,nullptr,nullptr,2048,gemb,cbuf,xn,h_all,t);
  }
  // logits = h_all @ out_w^T + out_b  (2560 x 30016->30000, K=512) -> d_out
  gemm_bt<2><<<dim3(235,20),256,0,stream>>>(h_all,512,outw_bf,512,512,
      out_b,out,nullptr,30000,nullptr,nullptr,nullptr,nullptr,0);
}

// Round 7
// 1244.697 us; speedup vs baseline: 1.9646x; 1.4444x over previous
//
#include <hip/hip_runtime.h>
#include <stdint.h>
#include <stddef.h>

typedef unsigned short u16;
typedef __attribute__((ext_vector_type(8))) short short8;
typedef __attribute__((ext_vector_type(4))) float f32x4;

#define DEV static __device__ __forceinline__

DEV float bf2f(u16 u){ return __uint_as_float(((unsigned)u)<<16); }
DEV u16 f2bf(float f){ unsigned x=__float_as_uint(f); return (u16)((x + 0x7fffu + ((x>>16)&1u))>>16); }

DEV float wsum(float v){
#pragma unroll
  for(int o=32;o;o>>=1) v += __shfl_xor(v,o);
  return v;
}
DEV float wmax(float v){
#pragma unroll
  for(int o=32;o;o>>=1) v = fmaxf(v,__shfl_xor(v,o));
  return v;
}
DEV float sigm(float x){ return __fdividef(1.f, 1.f+__expf(-x)); }
DEV float tanhx(float x){ float e=__expf(-2.f*fabsf(x)); float t=__fdividef(1.f-e,1.f+e); return x<0.f?-t:t; }

DEV f32x4 mfma16(short8 a, short8 b, f32x4 c){
  asm("v_mfma_f32_16x16x32_bf16 %0, %1, %2, %0" : "+v"(c) : "v"(a), "v"(b));
  return c;
}
DEV void gll16(const void* g, void* l){
  __builtin_amdgcn_global_load_lds((const __attribute__((address_space(1))) void*)g,
                                   (__attribute__((address_space(3))) void*)l, 16, 0, 0);
}

DEV void pack8(u16* dst, const float* src){
  const float4 a=*(const float4*)(src);
  const float4 b=*(const float4*)(src+4);
  short8 o;
  o[0]=(short)f2bf(a.x); o[1]=(short)f2bf(a.y); o[2]=(short)f2bf(a.z); o[3]=(short)f2bf(a.w);
  o[4]=(short)f2bf(b.x); o[5]=(short)f2bf(b.y); o[6]=(short)f2bf(b.z); o[7]=(short)f2bf(b.w);
  *(short8*)dst=o;
}
DEV void zero8(u16* dst){
  short8 z;
#pragma unroll
  for(int e=0;e<8;++e) z[e]=0;
  *(short8*)dst=z;
}

// ---------------------------------------------------------------------------
// setup: fp32->bf16 casts, weight reorders, embedding gather, combined bias.
// Gate rows unit-major: new row r <-> orig row o=((r&3)<<9)+(r>>2).
// ---------------------------------------------------------------------------
__global__ __launch_bounds__(256) void setup_cast(
  const float* __restrict__ feats, const int* __restrict__ captions,
  const float* __restrict__ embW, const float* __restrict__ Wf_w,
  const float* __restrict__ Wh_w, const float* __restrict__ W_ih,
  const float* __restrict__ W_hh, const float* __restrict__ b_ih,
  const float* __restrict__ b_hh, const float* __restrict__ out_w,
  u16* __restrict__ feats_bf, u16* __restrict__ outw_bf, u16* __restrict__ Wc,
  u16* __restrict__ WihE, u16* __restrict__ embx, u16* __restrict__ Whw_bf,
  u16* __restrict__ Wf_bf, float* __restrict__ bias_comb)
{
  const long long o0=12845056LL,o1=28246016LL,o2=30343168LL,o3=31391744LL,
                  o4=32702464LL,o5=32964608LL,o6=33226752LL,total=33228800LL;
  for (long long i8=((long long)blockIdx.x*256+threadIdx.x)*8; i8<total;
       i8+=(long long)gridDim.x*256*8){
    const long long i=i8;
    if (i<o0){ pack8(feats_bf+i, feats+i); }
    else if (i<o1){ const long long j=i-o0; const int r=(int)(j>>9);
      if (r<30000) pack8(outw_bf+j, out_w+j); else zero8(outw_bf+j); }
    else if (i<o2){ const long long j=i-o1; const int r=(int)(j>>10), k=(int)(j&1023);
      const int o=((r&3)<<9)+(r>>2);
      const float* s=(k<512)? (W_ih+(size_t)o*1024+512+k) : (W_hh+(size_t)o*512+(k-512));
      pack8(Wc+j, s); }
    else if (i<o3){ const long long j=i-o2; const int r=(int)(j>>9), k=(int)(j&511);
      const int o=((r&3)<<9)+(r>>2);
      pack8(WihE+j, W_ih+(size_t)o*1024+k); }
    else if (i<o4){ const long long j=i-o3; const int m=(int)(j>>9), e=(int)(j&511);
      const int b=m/20, tt=m-b*20; const int idx=captions[b*21+tt];
      if (idx) pack8(embx+j, embW+(size_t)idx*512+e); else zero8(embx+j); }
    else if (i<o5){ const long long j=i-o4; pack8(Whw_bf+j, Wh_w+j); }
    else if (i<o6){ const long long j=i-o5; pack8(Wf_bf+j, Wf_w+j); }
    else { const long long j=i-o6;
      for(int e=0;e<8;++e){ const int r=(int)(j+e); const int o=((r&3)<<9)+(r>>2);
        bias_comb[r]=b_ih[o]+b_hh[o]; } }
  }
}

// ---------------------------------------------------------------------------
// prep: gfeat = mean(feats), h0/c0. h0 (bf16) -> xs h-slot, c0 (fp32) -> cbuf.
// ---------------------------------------------------------------------------
__global__ __launch_bounds__(256) void prep(
  const float* __restrict__ feats, const float* __restrict__ init_w,
  const float* __restrict__ init_b, const float* __restrict__ initc_w,
  const float* __restrict__ initc_b, u16* __restrict__ xs0, float* __restrict__ cbuf)
{
  const int b=blockIdx.x, tid=threadIdx.x, lane=tid&63, w=tid>>6;
  __shared__ float gf[512];
  const float* fb=feats+(size_t)b*196*512;
  float a0=0.f,a1=0.f;
  for(int n=0;n<196;++n){ a0+=fb[(size_t)n*512+tid]; a1+=fb[(size_t)n*512+tid+256]; }
  gf[tid]=a0*(1.f/196.f); gf[tid+256]=a1*(1.f/196.f);
  __syncthreads();
  const int kb=lane*8;
  float g8[8];
#pragma unroll
  for(int e=0;e<8;++e) g8[e]=gf[kb+e];
  for(int j=w*128;j<w*128+128;++j){
    const float* r1=init_w+(size_t)j*512+kb;
    const float* r2=initc_w+(size_t)j*512+kb;
    float s1=0.f,s2=0.f;
#pragma unroll
    for(int e=0;e<8;++e){ s1+=g8[e]*r1[e]; s2+=g8[e]*r2[e]; }
    s1=wsum(s1); s2=wsum(s2);
    if(lane==(j&63)){ xs0[b*1024+512+j]=f2bf(s1+init_b[j]); cbuf[b*512+j]=s2+initc_b[j]; }
  }
}

// ---------------------------------------------------------------------------
// attn_step: 128 blocks x 1024 threads (16 waves).
// Prologue (t>0): LSTM for step t-1 — thread u sums gemb + 4 gpart K-slice
// partials (float4), applies gate nonlinearities, updates cbuf, writes h(t-1)
// to xs h-slot (bf16, for gates GEMM), h_all, and LDS hsf.
// Then: hproj (wave-row dots), scores (paired-n ILP, fast exact tanh via
// v·tanh(x)=v-2v/(e^{2x}+1)), softmax(196), ctx -> xs ctx-slot.
// ---------------------------------------------------------------------------
__global__ __launch_bounds__(1024) void attn_step(
  const u16* __restrict__ fproj, const u16* __restrict__ feats_bf,
  u16* __restrict__ xs, const u16* __restrict__ Whw,
  const float* __restrict__ Whb, const float* __restrict__ vw,
  const float* __restrict__ vb, const float* __restrict__ gemb,
  const float* __restrict__ gpart, float* __restrict__ cbuf,
  u16* __restrict__ h_all, int t)
{
  const int b=blockIdx.x, tid=threadIdx.x, lane=tid&63, w=tid>>6;
  __shared__ float part[16][512];
  __shared__ float hsf[512], hp[512], sc[208], red[16];
  if (t>0){
    if (tid<512){
      const int u=tid;
      float4 g4=*(const float4*)&gemb[((size_t)b*20+(t-1))*2048+u*4];
#pragma unroll
      for(int kz=0;kz<4;++kz){
        const float4 p=*(const float4*)&gpart[((size_t)kz*128+b)*2048+u*4];
        g4.x+=p.x; g4.y+=p.y; g4.z+=p.z; g4.w+=p.w;
      }
      const float cn=sigm(g4.y)*cbuf[b*512+u]+sigm(g4.x)*tanhx(g4.z);
      const float hn=sigm(g4.w)*tanhx(cn);
      cbuf[b*512+u]=cn;
      const u16 hb=f2bf(hn);
      xs[b*1024+512+u]=hb;
      h_all[((size_t)b*20+(t-1))*512+u]=hb;
      hsf[u]=bf2f(hb);
    }
  } else {
    if (tid<512) hsf[tid]=bf2f(xs[b*1024+512+tid]);
  }
  __syncthreads();
  const int kb=lane*8;
  float h8[8];
#pragma unroll
  for(int e=0;e<8;++e) h8[e]=hsf[kb+e];
  // hproj: wave w owns rows [32w, 32w+32), 2 rows per iteration
  for(int jj=0;jj<32;jj+=2){
    const int j=w*32+jj;
    short8 w0=*(const short8*)(Whw+(size_t)j*512+kb);
    short8 w1=*(const short8*)(Whw+(size_t)(j+1)*512+kb);
    float s0=0.f,s1=0.f;
#pragma unroll
    for(int e=0;e<8;++e){
      s0+=h8[e]*bf2f((u16)w0[e]);
      s1+=h8[e]*bf2f((u16)w1[e]);
    }
    s0=wsum(s0); s1=wsum(s1);
    if(lane==0){ hp[j]=s0+Whb[j]; hp[j+1]=s1+Whb[j+1]; }
  }
  __syncthreads();
  // scores: v·tanh(f+p) = v - 2v/(exp(2(f+p))+1); per-lane sv absorbs the v term
  float p2[8], vm2[8];
  float sv=0.f;
#pragma unroll
  for(int e=0;e<8;++e){
    const float p=hp[kb+e], v=vw[kb+e];
    p2[e]=2.f*p; vm2[e]=-2.f*v; sv+=v;
  }
  const float vb0=vb[0];
#pragma unroll
  for(int i=0;i<12;i+=2){
    const int n0=w+16*i, n1=n0+16;
    short8 f0=*(const short8*)(fproj+((size_t)b*196+n0)*512+kb);
    short8 f1=*(const short8*)(fproj+((size_t)b*196+n1)*512+kb);
    float s0=sv, s1=sv;
#pragma unroll
    for(int e=0;e<8;++e){
      const float x0=fmaf(bf2f((u16)f0[e]),2.f,p2[e]);
      const float x1=fmaf(bf2f((u16)f1[e]),2.f,p2[e]);
      s0+=__fdividef(vm2[e],__expf(x0)+1.f);
      s1+=__fdividef(vm2[e],__expf(x1)+1.f);
    }
    s0=wsum(s0); s1=wsum(s1);
    if(lane==0){ sc[n0]=s0+vb0; sc[n1]=s1+vb0; }
  }
  {
    const int n=w+192;
    if (n<196){
      short8 f0=*(const short8*)(fproj+((size_t)b*196+n)*512+kb);
      float s0=sv;
#pragma unroll
      for(int e=0;e<8;++e){
        const float x0=fmaf(bf2f((u16)f0[e]),2.f,p2[e]);
        s0+=__fdividef(vm2[e],__expf(x0)+1.f);
      }
      s0=wsum(s0);
      if(lane==0) sc[n]=s0+vb0;
    }
  }
  __syncthreads();
  // softmax over 196
  float xv=(tid<196)? sc[tid] : -3.0e38f;
  float mx=wmax(xv);
  if(lane==0) red[w]=mx;
  __syncthreads();
  float mm=red[0];
#pragma unroll
  for(int i=1;i<16;++i) mm=fmaxf(mm,red[i]);
  float pv=(tid<196)? __expf(xv-mm) : 0.f;
  float ps=wsum(pv);
  __syncthreads();
  if(lane==0) red[w]=ps;
  __syncthreads();
  float tot=red[0];
#pragma unroll
  for(int i=1;i<16;++i) tot+=red[i];
  if(tid<196) sc[tid]=__fdividef(pv,tot);
  __syncthreads();
  // ctx partials: wave w accumulates n = w + 16*i
  float a8[8];
#pragma unroll
  for(int e=0;e<8;++e) a8[e]=0.f;
  for(int n=w;n<196;n+=16){
    short8 fv=*(const short8*)(feats_bf+((size_t)b*196+n)*512+kb);
    const float wn=sc[n];
#pragma unroll
    for(int e=0;e<8;++e) a8[e]+=wn*bf2f((u16)fv[e]);
  }
  *(float4*)&part[w][kb]  =*(float4*)&a8[0];
  *(float4*)&part[w][kb+4]=*(float4*)&a8[4];
  __syncthreads();
  if (tid<512){
    float s=0.f;
#pragma unroll
    for(int i=0;i<16;++i) s+=part[i][tid];
    xs[b*1024+tid]=f2bf(s);
  }
}

// ---------------------------------------------------------------------------
// lstm_fin: LSTM for the final step (t=19) — h_all only.
// ---------------------------------------------------------------------------
__global__ __launch_bounds__(512) void lstm_fin(
  const float* __restrict__ gemb, const float* __restrict__ gpart,
  const float* __restrict__ cbuf, u16* __restrict__ h_all)
{
  const int b=blockIdx.x, u=threadIdx.x;
  float4 g4=*(const float4*)&gemb[((size_t)b*20+19)*2048+u*4];
#pragma unroll
  for(int kz=0;kz<4;++kz){
    const float4 p=*(const float4*)&gpart[((size_t)kz*128+b)*2048+u*4];
    g4.x+=p.x; g4.y+=p.y; g4.z+=p.z; g4.w+=p.w;
  }
  const float cn=sigm(g4.y)*cbuf[b*512+u]+sigm(g4.x)*tanhx(g4.z);
  const float hn=sigm(g4.w)*tanhx(cn);
  h_all[((size_t)b*20+19)*512+u]=f2bf(hn);
}

// ---------------------------------------------------------------------------
// gemm_bt: C[M,N] = A[M,K] * B[N,K]^T, 128x128 tile, m97 structure.
// MODE 0: bf16 out + bias   MODE 1: f32 out + bias   MODE 2: f32 + col guard
// MODE 4: K-split partial (blockIdx.y = K-slice kz, base += kz*256, bm=0;
//         f32 partial -> outf[kz*128 + r][c], no bias)
// ---------------------------------------------------------------------------
template<int MODE>
__global__ __launch_bounds__(256) void gemm_bt(
  const u16* __restrict__ A, int lda, const u16* __restrict__ Bw, int ldb, int K,
  const float* __restrict__ bias, float* __restrict__ outf, u16* __restrict__ outb,
  int ncols)
{
  const int bm=(MODE==4)? 0 : blockIdx.y*128;
  const int kz=(MODE==4)? blockIdx.y : 0;
  const int bn=blockIdx.x*128;
  const u16* __restrict__ Ap=A +(size_t)kz*256;
  const u16* __restrict__ Bp=Bw+(size_t)kz*256;
  const int tid=threadIdx.x, lane=tid&63, wave=tid>>6;
  const int wr=(wave>>1)*64, wc=(wave&1)*64;
  __shared__ u16 As[128*32], Bs[128*32];
  f32x4 acc[4][4]={};
  const int srow=tid>>2, scol=(tid&3)*8;
  for(int k0=0;k0<K;k0+=32){
    gll16(Ap+(size_t)(bm+srow)*lda    +k0+scol, As+tid*8);
    gll16(Ap+(size_t)(bm+64+srow)*lda +k0+scol, As+2048+tid*8);
    gll16(Bp+(size_t)(bn+srow)*ldb    +k0+scol, Bs+tid*8);
    gll16(Bp+(size_t)(bn+64+srow)*ldb +k0+scol, Bs+2048+tid*8);
    __syncthreads();
    short8 af[4], bfr[4];
    const int ro=lane&15, ko=(lane>>4)*8;
#pragma unroll
    for(int m=0;m<4;++m) af[m]=*(const short8*)(As+(wr+m*16+ro)*32+ko);
#pragma unroll
    for(int n=0;n<4;++n) bfr[n]=*(const short8*)(Bs+(wc+n*16+ro)*32+ko);
#pragma unroll
    for(int m=0;m<4;++m)
#pragma unroll
      for(int n=0;n<4;++n) acc[m][n]=mfma16(af[m],bfr[n],acc[m][n]);
    __syncthreads();
  }
  asm volatile("s_nop 7\ns_nop 7\ns_nop 7");  // MFMA->VALU hazard guard
  const int ro4=(lane>>4)*4, co=lane&15;
#pragma unroll
  for(int m=0;m<4;++m)
#pragma unroll
    for(int n=0;n<4;++n)
#pragma unroll
      for(int j=0;j<4;++j){
        const int r=bm+wr+m*16+ro4+j, c=bn+wc+n*16+co;
        if constexpr (MODE==0)      outb[(size_t)r*ncols+c]=f2bf(acc[m][n][j]+bias[c]);
        else if constexpr (MODE==1) outf[(size_t)r*ncols+c]=acc[m][n][j]+bias[c];
        else if constexpr (MODE==2){ if (c<ncols) outf[(size_t)r*ncols+c]=acc[m][n][j]+bias[c]; }
        else                        outf[((size_t)kz*128+r)*ncols+c]=acc[m][n][j];
      }
}

// ---------------------------------------------------------------------------
extern "C" void kernel_launch(void* const* d_in, const int* in_sizes, int n_in,
                              void* d_out, int out_size, void* d_ws, size_t ws_size,
                              hipStream_t stream) {
  const float* feats   =(const float*)d_in[0];
  const int*   captions=(const int*)  d_in[1];
  const float* embW    =(const float*)d_in[2];
  const float* Wf_w    =(const float*)d_in[3];
  const float* Wf_b    =(const float*)d_in[4];
  const float* Wh_w    =(const float*)d_in[5];
  const float* Wh_b    =(const float*)d_in[6];
  const float* v_w     =(const float*)d_in[7];
  const float* v_b     =(const float*)d_in[8];
  const float* W_ih    =(const float*)d_in[9];
  const float* W_hh    =(const float*)d_in[10];
  const float* b_ih    =(const float*)d_in[11];
  const float* b_hh    =(const float*)d_in[12];
  const float* init_w  =(const float*)d_in[13];
  const float* init_b  =(const float*)d_in[14];
  const float* initc_w =(const float*)d_in[15];
  const float* initc_b =(const float*)d_in[16];
  const float* out_w   =(const float*)d_in[17];
  const float* out_b   =(const float*)d_in[18];
  float* out=(float*)d_out;
  char* ws=(char*)d_ws;

  u16*   feats_bf =(u16*)  (ws+0);
  u16*   fproj    =(u16*)  (ws+25690112);
  u16*   outw_bf  =(u16*)  (ws+51380224);
  u16*   Wc       =(u16*)  (ws+82182144);
  u16*   WihE     =(u16*)  (ws+86376448);
  u16*   Whw_bf   =(u16*)  (ws+88473600);
  u16*   Wf_bf    =(u16*)  (ws+88997888);
  u16*   embx     =(u16*)  (ws+89522176);
  u16*   h_all    =(u16*)  (ws+92143616);
  u16*   xs0      =(u16*)  (ws+94765056);
  float* gemb     =(float*)(ws+95289344);
  float* cbuf     =(float*)(ws+116260864);
  float* bias_comb=(float*)(ws+116523008);
  float* gpart    =(float*)(ws+116531200);

  setup_cast<<<4096,256,0,stream>>>(feats,captions,embW,Wf_w,Wh_w,W_ih,W_hh,b_ih,b_hh,out_w,
                                    feats_bf,outw_bf,Wc,WihE,embx,Whw_bf,Wf_bf,bias_comb);
  prep<<<128,256,0,stream>>>(feats,init_w,init_b,initc_w,initc_b,xs0,cbuf);
  // fproj = feats_bf @ Wf^T + Wf_b  (25088 x 512, K=512) -> bf16
  gemm_bt<0><<<dim3(4,196),256,0,stream>>>(feats_bf,512,Wf_bf,512,512,
      Wf_b,nullptr,fproj,512);
  // gemb = embx @ WihE^T + (b_ih+b_hh)  (2560 x 2048, K=512) -> f32
  gemm_bt<1><<<dim3(16,20),256,0,stream>>>(embx,512,WihE,512,512,
      bias_comb,gemb,nullptr,2048);

  for(int t=0;t<20;++t){
    attn_step<<<128,1024,0,stream>>>(fproj,feats_bf,xs0,Whw_bf,Wh_b,v_w,v_b,
                                     gemb,gpart,cbuf,h_all,t);
    // gates partials: xs(128x1024) @ Wc^T(2048x1024), K-split 4x256 -> gpart
    gemm_bt<4><<<dim3(16,4),256,0,stream>>>(xs0,1024,Wc,1024,256,
        nullptr,gpart,nullptr,2048);
  }
  lstm_fin<<<128,512,0,stream>>>(gemb,gpart,cbuf,h_all);
  // logits = h_all @ out_w^T + out_b  (2560 x 30016->30000, K=512) -> d_out
  gemm_bt<2><<<dim3(235,20),256,0,stream>>>(h_all,512,outw_bf,512,512,
      out_b,out,nullptr,30000);
}